// Round 6
// baseline (81675.897 us; speedup 1.0000x reference)
//
#include <hip/hip_runtime.h>

#define DI __device__ __forceinline__

typedef __bf16  bf16x8 __attribute__((ext_vector_type(8)));
typedef float   f32x4  __attribute__((ext_vector_type(4)));
typedef unsigned short u16;
typedef unsigned int   u32;
typedef unsigned long long u64;

DI u16 f2bf(float f){ u32 u=__float_as_uint(f); u32 r=0x7fffu+((u>>16)&1u); return (u16)((u+r)>>16); }
DI float bf2f(u16 h){ return __uint_as_float(((u32)h)<<16); }
DI u32 umin2(u32 a, u32 b){ return a<b?a:b; }

union U16x8 { u16 u[8]; uint4 v; };
union ABu   { uint4 u; bf16x8 b; };

#define MFMA(a,b,c) __builtin_amdgcn_mfma_f32_16x16x32_bf16((a),(b),(c),0,0,0)
#define SCHED0() __builtin_amdgcn_sched_barrier(0)
#define SBAR()   __builtin_amdgcn_s_barrier()

// coherent (L3-visible) 16B load — cross-XCD h-state
DI void aload(uint4& d, const void* p){
  asm volatile("global_load_dwordx4 %0, %1, off sc0 sc1" : "=&v"(d) : "v"(p) : "memory");
}
// plain cached 16B load — static weights (L2-resident)
DI void wloadv(uint4& d, const void* p){
  asm volatile("global_load_dwordx4 %0, %1, off" : "=&v"(d) : "v"(p) : "memory");
}
// coherent 8B store (64-bit scalar input: valid "v" constraint)
DI void st8c(void* p, u64 v){
  asm volatile("global_store_dwordx2 %0, %1, off sc0 sc1" :: "v"(p), "v"(v) : "memory");
}
DI void stflag(void* p, u32 v){
  asm volatile("global_store_dword %0, %1, off sc0 sc1" :: "v"(p), "v"(v) : "memory");
}
template<int N> DI void vw(){ asm volatile("s_waitcnt vmcnt(%0)" :: "n"(N) : "memory"); }
DI void lgkm0(){ asm volatile("s_waitcnt lgkmcnt(0)" ::: "memory"); }
DI void vwn(int n){
  switch(n){
    case 0:  vw<0>();  break; case 4:  vw<4>();  break; case 8:  vw<8>();  break;
    case 12: vw<12>(); break; case 16: vw<16>(); break; case 20: vw<20>(); break;
    case 25: vw<25>(); break; case 26: vw<26>(); break; case 27: vw<27>(); break;
    default: vw<28>(); break;
  }
}
// poll 4 single-writer flags until all >= tgt
DI void spin4(const u32* f, u32 tgt){
  for(;;){
    uint4 a;
    asm volatile("global_load_dwordx4 %0, %1, off sc0 sc1\n\ts_waitcnt vmcnt(0)"
                 : "=&v"(a) : "v"(f) : "memory");
    if (umin2(umin2(a.x,a.y),umin2(a.z,a.w)) >= tgt) return;
    __builtin_amdgcn_s_sleep(2);
  }
}

// ---- problem constants
#define Tn 512
#define Bn 2048
#define Fn 16
#define Hn 512

// ---- workspace layout (bytes)
#define OFF_WH0   0ull
#define OFF_WI1   3145728ull
#define OFF_WH1   6291456ull
#define OFF_WI0   9437184ull
#define OFF_H0HI  9633792ull
#define OFF_H0LO  13828096ull
#define OFF_H1HI  18022400ull
#define OFF_H1LO  22216704ull
#define OFF_FLAGS 26411008ull

#define XOFF  8192
#define TROFF 10240
#define PLANE 1048576   // u16 per parity plane (2048x512)

// =====================================================================
// prep (round-1 proven): fp32 [3H x 512] -> frag-linear bf16 hi/lo pairs.
// pair = {hi 1KB, lo 1KB}; pairidx = (g*32+(j>>4))*16 + k32;
// lane = (j&15)+((k>>3)&3)*16, 8 u16/lane.
// =====================================================================
__global__ __launch_bounds__(256) void prep_w(const float* __restrict__ w0,
                                              const float* __restrict__ w1,
                                              const float* __restrict__ w2,
                                              u16* __restrict__ dst){
  int tid = blockIdx.x*256 + threadIdx.x;        // 294912
  int p = tid / 98304, rem = tid % 98304;        // 0=WH0 1=WI1 2=WH1
  int g = rem / 32768, rem2 = rem % 32768;
  int j = rem2 / 64,   k8 = rem2 % 64;
  const float* src = (p==0)?w0:((p==1)?w1:w2);
  const float* s = src + (size_t)(g*Hn + j)*Hn + k8*8;
  U16x8 hi, lo;
#pragma unroll
  for (int i=0;i<8;++i){ float v = s[i]; u16 h = f2bf(v); hi.u[i]=h; lo.u[i]=f2bf(v - bf2f(h)); }
  size_t pairidx = (size_t)(g*32 + (j>>4))*16 + (k8>>2);
  u16* d = dst + (size_t)p*1572864 + pairidx*1024 + (size_t)((j&15) + (k8&3)*16)*8;
  *(uint4*)d = hi.v;
  *(uint4*)(d + 512) = lo.v;
}

// W_ih0 [1536x16] -> hi/lo pairs, [w|w] duplicated in both k16-halves
__global__ __launch_bounds__(256) void prep_wi0(const float* __restrict__ w,
                                                u16* __restrict__ dst){
  int tid = blockIdx.x*256 + threadIdx.x;        // 3072
  if (tid >= 3072) return;
  int gcol = tid >> 1, k8 = tid & 1;
  const float* sp = w + (size_t)gcol*16 + k8*8;
  U16x8 H, L;
#pragma unroll
  for (int i=0;i<8;++i){ float f = sp[i]; u16 h = f2bf(f); H.u[i]=h; L.u[i]=f2bf(f - bf2f(h)); }
  int jj = gcol & 511;
  int jg = (gcol>>9)*32 + (jj>>4);
  u16* base = dst + (size_t)jg*1024;
  size_t o1 = (size_t)((jj&15) + k8*16)*8, o2 = (size_t)((jj&15) + (2+k8)*16)*8;
  *(uint4*)(base + o1) = H.v;        *(uint4*)(base + o2) = H.v;
  *(uint4*)(base + 512 + o1) = L.v;  *(uint4*)(base + 512 + o2) = L.v;
}

// zero parity-1 h planes (initial state) + flags
__global__ __launch_bounds__(256) void zero_ws(char* __restrict__ ws){
  int tid = blockIdx.x*256 + threadIdx.x;
  if (tid >= 524416) return;
  uint4 z = {0u,0u,0u,0u};
  size_t o;
  if      (tid < 131072) o = OFF_H0HI + 2097152 + (size_t)tid*16;
  else if (tid < 262144) o = OFF_H0LO + 2097152 + (size_t)(tid-131072)*16;
  else if (tid < 393216) o = OFF_H1HI + 2097152 + (size_t)(tid-262144)*16;
  else if (tid < 524288) o = OFF_H1LO + 2097152 + (size_t)(tid-393216)*16;
  else                   o = OFF_FLAGS + (size_t)(tid-524288)*16;
  *(uint4*)(ws + o) = z;
}

struct PA {
  const u16 *WI0, *WH0, *WI1, *WH1;
  const float *x;
  u16 *H0HI, *H0LO, *H1HI, *H1LO;
  u32 *flags;                       // [2][64 mt][4 jt], monotone step counts
  const float *bi0,*bh0,*bi1,*bh1;
};

// =====================================================================
// One layer-step. Block = 256 thr (4 waves), tile 32 rows x (128 j x 3 gates).
// Wave wv = (mi=wv>>1, hl=wv&1) A-quadrant loader; owns jfl groups wv*2+{0,1}.
// A (h hi/lo, sc0sc1) -> 1 aload/wave/t -> 2-slot LDS broadcast.
// W -> regs direct: r,z hi-only (2-product), n hi+lo (3-product).
// acc[mi][jfl][0]=r(i+h) [1]=z(i+h) [2]=i_n [3]=h_n
// =====================================================================
template<int L>
DI void layer_run(const PA& a, int s, char* smem, int tid, int lane, int wv,
                  int mt, int jt,
                  const u16* AhiI, const u16* AloI,
                  const u16* AhiH, const u16* AloH,
                  u16* OHI, u16* OLO,
                  const float (&SR)[2], const float (&SZ)[2],
                  const float (&BIN)[2], const float (&BHN)[2],
                  float* hp)
{
  constexpr int NT = (L==0) ? 17 : 32;
  const u16* Wi = (L==0) ? a.WI0 : a.WI1;
  const u16* Wh = (L==0) ? a.WH0 : a.WH1;
  const int mi_w = wv >> 1, hl_w = wv & 1;
  const u16* baseI = hl_w ? AloI : AhiI;
  const u16* baseH = hl_w ? AloH : AhiH;

  uint4 areg[5];
  uint4 wreg[32];
  f32x4 acc[2][2][4];
#pragma unroll
  for (int mi=0;mi<2;++mi)
#pragma unroll
    for (int jfl=0;jfl<2;++jfl)
#pragma unroll
      for (int o=0;o<4;++o){ f32x4 z={0.f,0.f,0.f,0.f}; acc[mi][jfl][o]=z; }

  auto issueA = [&](int t){
    const u16* ph; int k32;
    if (L==0){ ph = baseH; k32 = (t==0)?0:(t-1); }       // t=0 dummy (x path)
    else if (t < 16){ ph = baseI; k32 = t; }
    else { ph = baseH; k32 = t-16; }
    size_t off = ((size_t)((mt*2 + mi_w)*16 + k32))*512 + (size_t)lane*8;
    aload(areg[t%5], ph + off);
  };
  auto issueW = [&](int t){
    const u16* wb; int k32 = 0; bool dup = false;
    if (L==0){ if (t==0){ wb=Wi; dup=true; } else { wb=Wh; k32=t-1; } }
    else { if (t<16){ wb=Wi; k32=t; } else { wb=Wh; k32=t-16; } }
    uint4* d = &wreg[(t&3)*8];
#pragma unroll
    for (int jfl=0; jfl<2; ++jfl){
      int jq = jt*8 + wv*2 + jfl;
      size_t pr_ = dup ? ((size_t)jq*1024)      : ((size_t)(jq*16 + k32))*1024;
      size_t pz_ = dup ? ((size_t)(32+jq)*1024) : ((size_t)((32+jq)*16 + k32))*1024;
      size_t pn_ = dup ? ((size_t)(64+jq)*1024) : ((size_t)((64+jq)*16 + k32))*1024;
      size_t lo8 = (size_t)lane*8;
      wloadv(d[jfl*4+0], wb + pr_ + lo8);        // r hi
      wloadv(d[jfl*4+1], wb + pz_ + lo8);        // z hi
      wloadv(d[jfl*4+2], wb + pn_ + lo8);        // n hi
      wloadv(d[jfl*4+3], wb + pn_ + 512 + lo8);  // n lo
    }
  };
  auto stageA = [&](int t){
    *(uint4*)(smem + (t&1)*4096 + wv*1024 + (size_t)lane*16) = areg[t%5];
  };
  auto compute = [&](int t){
    const char* sl = smem + (t&1)*4096;
    const uint4* ws_ = &wreg[(t&3)*8];
    const int gn = (L==0) ? ((t==0)?2:3) : ((t<16)?2:3);
    if (L==0 && t==0){
      bf16x8 ax[2];
      ax[0] = *(const bf16x8*)(smem + XOFF + (size_t)lane*16);
      ax[1] = *(const bf16x8*)(smem + XOFF + 1024 + (size_t)lane*16);
#pragma unroll
      for (int jfl=0;jfl<2;++jfl){
        ABu wr_,wz_,wnh,wnl;
        wr_.u=ws_[jfl*4]; wz_.u=ws_[jfl*4+1]; wnh.u=ws_[jfl*4+2]; wnl.u=ws_[jfl*4+3];
#pragma unroll
        for (int mi=0;mi<2;++mi){
          acc[mi][jfl][0] = MFMA(ax[mi], wr_.b, acc[mi][jfl][0]);
          acc[mi][jfl][1] = MFMA(ax[mi], wz_.b, acc[mi][jfl][1]);
          acc[mi][jfl][2] = MFMA(ax[mi], wnh.b, acc[mi][jfl][2]);
          acc[mi][jfl][2] = MFMA(ax[mi], wnl.b, acc[mi][jfl][2]);
        }
      }
    } else {
      bf16x8 ah[2], al[2];
      ah[0] = *(const bf16x8*)(sl + (size_t)lane*16);
      al[0] = *(const bf16x8*)(sl + 1024 + (size_t)lane*16);
      ah[1] = *(const bf16x8*)(sl + 2048 + (size_t)lane*16);
      al[1] = *(const bf16x8*)(sl + 3072 + (size_t)lane*16);
#pragma unroll
      for (int jfl=0;jfl<2;++jfl){
        ABu wr_,wz_,wnh,wnl;
        wr_.u=ws_[jfl*4]; wz_.u=ws_[jfl*4+1]; wnh.u=ws_[jfl*4+2]; wnl.u=ws_[jfl*4+3];
#pragma unroll
        for (int mi=0;mi<2;++mi){
          acc[mi][jfl][0] = MFMA(ah[mi], wr_.b, acc[mi][jfl][0]);
          acc[mi][jfl][0] = MFMA(al[mi], wr_.b, acc[mi][jfl][0]);
          acc[mi][jfl][1] = MFMA(ah[mi], wz_.b, acc[mi][jfl][1]);
          acc[mi][jfl][1] = MFMA(al[mi], wz_.b, acc[mi][jfl][1]);
          acc[mi][jfl][gn] = MFMA(ah[mi], wnh.b, acc[mi][jfl][gn]);
          acc[mi][jfl][gn] = MFMA(ah[mi], wnl.b, acc[mi][jfl][gn]);
          acc[mi][jfl][gn] = MFMA(al[mi], wnh.b, acc[mi][jfl][gn]);
        }
      }
    }
  };

  // ---- x stage (L0): 32 rows -> 2 subtiles, [x_hi k0-15 | x_lo k16-31]
  if (L==0 && tid < 64){
    int row = tid >> 1, half = tid & 1;
    const float* xr = a.x + (size_t)s*Bn*Fn + (size_t)(mt*32 + row)*Fn + half*8;
    U16x8 H, Lo;
#pragma unroll
    for (int i=0;i<8;++i){ float f = xr[i]; u16 h = f2bf(f); H.u[i]=h; Lo.u[i]=f2bf(f - bf2f(h)); }
    char* b0 = smem + XOFF + (row>>4)*1024;
    *(uint4*)(b0 + (size_t)((row&15) + half*16)*16)     = H.v;
    *(uint4*)(b0 + (size_t)((row&15) + (2+half)*16)*16) = Lo.v;
  }

  // ---- W prologue (static, hides under spin), spin, then A prologue
  issueW(0); issueW(1); issueW(2);
  if (tid == 0){
    const u32* F0 = a.flags + mt*4;
    if (L==0){ spin4(F0, (u32)s); }
    else { spin4(F0, (u32)(s+1)); spin4(a.flags + 256 + mt*4, (u32)s); }
  }
  lgkm0(); SCHED0();
  SBAR(); SCHED0();
  issueA(0); issueA(1); issueA(2); issueA(3); issueA(4);

  // ---- main loop (per-issue vmem ops: A=1, W=8; exact-FIFO counted waits)
#pragma unroll
  for (int t=0; t<NT; ++t){
    int aw = (t==0)?4 : (t==1)?12 : (t==2)?20 : (t==3)?28 : 27;
    vwn(aw); SCHED0();
    stageA(t);
    lgkm0(); SCHED0();
    SBAR(); SCHED0();
    if (t+5 < NT) issueA(t+5);
    if (t+3 < NT) issueW(t+3);
    if (t >= 3){
      int dW = NT-1-t;
      int tw = (dW>=5)?27 : (dW==4)?26 : (dW==3)?25 : (dW==2)?16 : (dW==1)?8 : 0;
      vwn(tw); SCHED0();
    }
    compute(t);
  }

  // ---- GRU epilogue -> LDS transpose -> coalesced coherent stores -> flag
  const int col = lane & 15, rg4 = (lane>>4)*4;
#pragma unroll
  for (int mi=0; mi<2; ++mi)
#pragma unroll
  for (int jfl=0; jfl<2; ++jfl){
    char* thi = smem + TROFF + (mi*4 + wv)*1024;
    char* tlo = thi + 8192;
#pragma unroll
    for (int r=0;r<4;++r){
      float pr  = acc[mi][jfl][0][r] + SR[jfl];
      float pz  = acc[mi][jfl][1][r] + SZ[jfl];
      float pin = acc[mi][jfl][2][r] + BIN[jfl];
      float phn = acc[mi][jfl][3][r] + BHN[jfl];
      float rg_ = 1.f/(1.f + __expf(-pr));
      float zg  = 1.f/(1.f + __expf(-pz));
      float e2  = __expf(2.f*(pin + rg_*phn));
      float nn  = 1.f - 2.f/(e2 + 1.f);            // tanh, overflow-safe
      int hx = (mi*2+jfl)*4 + r;
      float hv = hp[hx];
      float hn2 = (1.f - zg)*nn + zg*hv;
      hp[hx] = hn2;
      u16 hi = f2bf(hn2), lo = f2bf(hn2 - bf2f(hi));
      int off = ((rg4 + r) + (jfl*2 + (col>>3))*16)*16 + (col&7)*2;
      *(u16*)(thi + off) = hi;
      *(u16*)(tlo + off) = lo;
    }
  }
  lgkm0(); SCHED0();
  SBAR(); SCHED0();
  {
    int sI = tid >> 5;
    size_t gsub = ((size_t)((mt*2 + (sI>>2))*16) + (size_t)(jt*4 + (sI&3)))*512;
    size_t goff = (size_t)(tid & 31)*16;
    const char* shi = smem + TROFF + (size_t)tid*32;
    const char* slo = shi + 8192;
    u16* dh = OHI + gsub + goff;
    u16* dl = OLO + gsub + goff;
    st8c(dh,      *(const u64*)(shi));
    st8c(dh + 4,  *(const u64*)(shi+8));
    st8c(dh + 8,  *(const u64*)(shi+16));
    st8c(dh + 12, *(const u64*)(shi+24));
    st8c(dl,      *(const u64*)(slo));
    st8c(dl + 4,  *(const u64*)(slo+8));
    st8c(dl + 8,  *(const u64*)(slo+16));
    st8c(dl + 12, *(const u64*)(slo+24));
  }
  vw<0>(); SCHED0();
  SBAR(); SCHED0();
  if (tid == 0) stflag(a.flags + ((L==0)?0:256) + mt*4 + jt, (u32)(s+1));
}

// =====================================================================
// Persistent kernel: 256 blocks (1/CU via 84KB LDS), 512 steps x 2 layers.
// mt = bid>>2 (32-row group), jt = bid&3 (128-col slice; bid%8 ~ XCD).
// =====================================================================
__global__ __launch_bounds__(256, 1) void gru_persist(PA a){
  __shared__ __align__(16) char smem[86016];
  const int tid = threadIdx.x, lane = tid & 63, wv = tid >> 6;
  const int bid = blockIdx.x;
  const int jt = bid & 3, mt = bid >> 2;

  float SR0[2],SZ0[2],BIN0[2],BHN0[2],SR1[2],SZ1[2],BIN1[2],BHN1[2];
#pragma unroll
  for (int jfl=0;jfl<2;++jfl){
    int j = jt*128 + (wv*2+jfl)*16 + (lane&15);
    SR0[jfl]  = a.bi0[j] + a.bh0[j];
    SZ0[jfl]  = a.bi0[Hn+j] + a.bh0[Hn+j];
    BIN0[jfl] = a.bi0[2*Hn+j];
    BHN0[jfl] = a.bh0[2*Hn+j];
    SR1[jfl]  = a.bi1[j] + a.bh1[j];
    SZ1[jfl]  = a.bi1[Hn+j] + a.bh1[Hn+j];
    BIN1[jfl] = a.bi1[2*Hn+j];
    BHN1[jfl] = a.bh1[2*Hn+j];
  }
  float hp0[16], hp1[16];
#pragma unroll
  for (int i=0;i<16;++i){ hp0[i]=0.f; hp1[i]=0.f; }

#pragma unroll 1
  for (int s=0; s<Tn; ++s){
    const size_t P0 = (size_t)(s&1)*PLANE, P1 = (size_t)((s&1)^1)*PLANE;
    layer_run<0>(a, s, smem, tid, lane, wv, mt, jt,
                 nullptr, nullptr,
                 a.H0HI + P1, a.H0LO + P1,
                 a.H0HI + P0, a.H0LO + P0,
                 SR0, SZ0, BIN0, BHN0, hp0);
    layer_run<1>(a, s, smem, tid, lane, wv, mt, jt,
                 a.H0HI + P0, a.H0LO + P0,
                 a.H1HI + P1, a.H1LO + P1,
                 a.H1HI + P0, a.H1LO + P0,
                 SR1, SZ1, BIN1, BHN1, hp1);
  }
}

// final projection: out[b][o] = h1[b,:] . Wout[o,:] + bout[o]
__global__ __launch_bounds__(64) void outproj(const u16* __restrict__ h1hi,
                                              const u16* __restrict__ h1lo,
                                              const float* __restrict__ Wout,
                                              const float* __restrict__ bout,
                                              float* __restrict__ out){
  int b = blockIdx.x, l = threadIdx.x;
  float acc[8] = {0.f,0.f,0.f,0.f,0.f,0.f,0.f,0.f};
  for (int jj = l; jj < Hn; jj += 64){
    size_t fo = ((size_t)(b>>4)*16 + (jj>>5))*512 + (size_t)((b&15) + ((jj>>3)&3)*16)*8 + (jj&7);
    float hv = bf2f(h1hi[fo]) + bf2f(h1lo[fo]);
#pragma unroll
    for (int o=0;o<8;++o) acc[o] += hv * Wout[o*Hn + jj];
  }
#pragma unroll
  for (int o=0;o<8;++o){
#pragma unroll
    for (int off=32; off; off>>=1) acc[o] += __shfl_xor(acc[o], off);
  }
  if (l == 0){
#pragma unroll
    for (int o=0;o<8;++o) out[b*8+o] = acc[o] + bout[o];
  }
}

extern "C" void kernel_launch(void* const* d_in, const int* in_sizes, int n_in,
                              void* d_out, int out_size, void* d_ws, size_t ws_size,
                              hipStream_t stream){
  (void)in_sizes; (void)n_in; (void)out_size; (void)ws_size;
  const float* x    = (const float*)d_in[0];
  const float* Wih0 = (const float*)d_in[1];
  const float* Whh0 = (const float*)d_in[2];
  const float* bih0 = (const float*)d_in[3];
  const float* bhh0 = (const float*)d_in[4];
  const float* Wih1 = (const float*)d_in[5];
  const float* Whh1 = (const float*)d_in[6];
  const float* bih1 = (const float*)d_in[7];
  const float* bhh1 = (const float*)d_in[8];
  const float* Wout = (const float*)d_in[9];
  const float* bout = (const float*)d_in[10];
  char* ws = (char*)d_ws;

  prep_w  <<<1152, 256, 0, stream>>>(Whh0, Wih1, Whh1, (u16*)(ws + OFF_WH0));
  prep_wi0<<<  12, 256, 0, stream>>>(Wih0, (u16*)(ws + OFF_WI0));
  zero_ws <<<2049, 256, 0, stream>>>(ws);

  PA pa;
  pa.WI0 = (const u16*)(ws + OFF_WI0);
  pa.WH0 = (const u16*)(ws + OFF_WH0);
  pa.WI1 = (const u16*)(ws + OFF_WI1);
  pa.WH1 = (const u16*)(ws + OFF_WH1);
  pa.x = x;
  pa.H0HI = (u16*)(ws + OFF_H0HI); pa.H0LO = (u16*)(ws + OFF_H0LO);
  pa.H1HI = (u16*)(ws + OFF_H1HI); pa.H1LO = (u16*)(ws + OFF_H1LO);
  pa.flags = (u32*)(ws + OFF_FLAGS);
  pa.bi0 = bih0; pa.bh0 = bhh0; pa.bi1 = bih1; pa.bh1 = bhh1;

  gru_persist<<<256, 256, 0, stream>>>(pa);

  outproj<<<2048, 64, 0, stream>>>(
      (const u16*)(ws + OFF_H1HI) + PLANE,
      (const u16*)(ws + OFF_H1LO) + PLANE,
      Wout, bout, (float*)d_out);
}

// Round 8
// 30844.766 us; speedup vs baseline: 2.6480x; 2.6480x over previous
//
#include <hip/hip_runtime.h>

#define DI __device__ __forceinline__

typedef __bf16  bf16x8 __attribute__((ext_vector_type(8)));
typedef float   f32x4  __attribute__((ext_vector_type(4)));
typedef unsigned short u16;
typedef unsigned int   u32;

DI u16 f2bf(float f){ u32 u=__float_as_uint(f); u32 r=0x7fffu+((u>>16)&1u); return (u16)((u+r)>>16); }
DI float bf2f(u16 h){ return __uint_as_float(((u32)h)<<16); }

union U16x8 { u16 u[8]; uint4 v; };

#define MFMA(a,b,c) __builtin_amdgcn_mfma_f32_16x16x32_bf16((a),(b),(c),0,0,0)
#define SBAR()   __builtin_amdgcn_s_barrier()

// async global->LDS, 16B/lane, wave-uniform LDS base, plain cached path
DI void gload16(const void* g, void* l){
  __builtin_amdgcn_global_load_lds((const __attribute__((address_space(1))) u32*)g,
                                   (__attribute__((address_space(3))) u32*)l, 16, 0, 0);
}
template<int N> DI void vw(){ asm volatile("s_waitcnt vmcnt(%0)" :: "n"(N) : "memory"); }
DI void lgkm0(){ asm volatile("s_waitcnt lgkmcnt(0)" ::: "memory"); }
DI void vwn(int n){
  switch(n){
    case 0:  vw<0>();  break;
    case 4:  vw<4>();  break;
    case 6:  vw<6>();  break;
    case 8:  vw<8>();  break;
    default: vw<12>(); break;
  }
}
DI void spinw(u32* f, u32 tgt){
  while (__hip_atomic_load(f, __ATOMIC_RELAXED, __HIP_MEMORY_SCOPE_AGENT) < tgt)
    __builtin_amdgcn_s_sleep(8);
}

// ---- problem constants
#define Tn 512
#define Bn 2048
#define Hn 512

// ---- workspace layout (bytes). Hybrid W: per (jg,k32) 4 planes [r|z|nh|nl]
#define OFF_WH0   0ull
#define OFF_WI1   2097152ull
#define OFF_WH1   4194304ull
#define OFF_WI0   6291456ull
#define OFF_H0HI  6422528ull
#define OFF_H0LO  10616832ull
#define OFF_H1HI  14811136ull
#define OFF_H1LO  19005440ull
#define OFF_FLAGS 23199744ull
// end 23330816

#define PLANE 1048576   // u16 per parity plane (2048x512)
// LDS map: W 4x16KB [0,65536) | A 4x8KB [65536,98304) | X 4KB [98304,102400)
#define AOFF 65536
#define XOFF 98304

// =====================================================================
// prep_w: fp32 [1536 x 512] -> hybrid frag-linear subtiles.
// block(jg,k32) = 4 planes x 512 u16: 0=r 1=z 2=n-hi 3=n-lo.
// lane t64 = (j&15) + (k>>3)*16, 8 u16 (k&7) each.
// =====================================================================
__global__ __launch_bounds__(256) void prep_w(const float* __restrict__ w0,
                                              const float* __restrict__ w1,
                                              const float* __restrict__ w2,
                                              u16* __restrict__ dst){
  int tid = blockIdx.x*256 + threadIdx.x;        // 393216 total
  int p = tid / 131072, rem = tid % 131072;      // 0=WH0 1=WI1 2=WH1
  int sub = rem >> 6, t64 = rem & 63;
  int plane = sub & 3, k32 = (sub>>2) & 15, jg = sub >> 6;
  int g = (plane < 2) ? plane : 2;
  int jj = t64 & 15, koct = t64 >> 4;
  const float* src = (p==0)?w0:((p==1)?w1:w2);
  const float* sp = src + (size_t)(g*512 + jg*16 + jj)*512 + k32*32 + koct*8;
  U16x8 o;
#pragma unroll
  for (int i=0;i<8;++i){
    float v = sp[i]; u16 h = f2bf(v);
    o.u[i] = (plane==3) ? f2bf(v - bf2f(h)) : h;
  }
  u16* d = dst + (size_t)p*1048576 + ((size_t)((jg*16 + k32)*4 + plane))*512 + (size_t)t64*8;
  *(uint4*)d = o.v;
}

// W_ih0 [1536x16] -> per jg: 4 planes, [v|v] duplicated across k16-halves
__global__ __launch_bounds__(256) void prep_wi0(const float* __restrict__ w,
                                                u16* __restrict__ dst){
  int tid = blockIdx.x*256 + threadIdx.x;        // 8192 total
  if (tid >= 8192) return;
  int jg = tid >> 8, rem = tid & 255;
  int plane = rem >> 6, t64 = rem & 63;
  int jj = t64 & 15, koct = t64 >> 4, col8 = koct & 1;
  int g = (plane < 2) ? plane : 2;
  const float* sp = w + (size_t)(g*512 + jg*16 + jj)*16 + col8*8;
  U16x8 o;
#pragma unroll
  for (int i=0;i<8;++i){
    float v = sp[i]; u16 h = f2bf(v);
    o.u[i] = (plane==3) ? f2bf(v - bf2f(h)) : h;
  }
  u16* d = dst + ((size_t)(jg*4 + plane))*512 + (size_t)t64*8;
  *(uint4*)d = o.v;
}

// zero parity-1 h planes (initial state) + flags
__global__ __launch_bounds__(256) void zero_ws(char* __restrict__ ws){
  int tid = blockIdx.x*256 + threadIdx.x;
  if (tid >= 532480) return;
  uint4 z = {0u,0u,0u,0u};
  size_t o;
  if      (tid < 131072) o = OFF_H0HI + 2097152 + (size_t)tid*16;
  else if (tid < 262144) o = OFF_H0LO + 2097152 + (size_t)(tid-131072)*16;
  else if (tid < 393216) o = OFF_H1HI + 2097152 + (size_t)(tid-262144)*16;
  else if (tid < 524288) o = OFF_H1LO + 2097152 + (size_t)(tid-393216)*16;
  else                   o = OFF_FLAGS + (size_t)(tid-524288)*16;
  *(uint4*)(ws + o) = z;
}

struct PA {
  const u16 *WI0, *WH0, *WI1, *WH1;
  const float *x;
  u16 *H0HI, *H0LO, *H1HI, *H1LO;
  u32 *flags;                       // [2][512][32 mt] monotone publish counts
  const float *bi0,*bh0,*bi1,*bh1;
};

// =====================================================================
// One layer-step. Block 256 thr (4 waves), tile 64 rows x 64 hidden cols.
// Wave wv: owns jg = jt*4+wv (16 cols, all 4 m-frags) and stages m-frag wv.
// A (h hi/lo) + W both via global_load_lds, 6 VMEM/wave/t, depth-3,
// counted vmcnt ladder (t0:4 t1:8 steady:12 NT-2:6 NT-1:0), 1 barrier/t.
// acc[m][0]=r(i+h) [1]=z(i+h) [2]=i_n [3]=h_n
// h-coherence: plain loads/stores + release-publish / relaxed-spin+acquire.
// =====================================================================
template<int L>
DI void layer_run(const PA& a, int s, char* smem, int tid, int lane, int wv,
                  int mt, int jt,
                  const u16* AhiI, const u16* AloI,
                  const u16* AhiH, const u16* AloH,
                  u16* OHI, u16* OLO,
                  float SR, float SZ, float BIN, float BHN,
                  f32x4 (&hp)[4],
                  u32* sp1, u32* sp2, u32* pub)
{
  constexpr int NI = (L==0) ? 1 : 16;
  constexpr int NT = (L==0) ? 17 : 32;
  const u16* Wi = (L==0) ? a.WI0 : a.WI1;
  const u16* Wh = (L==0) ? a.WH0 : a.WH1;

  f32x4 acc[4][4];
#pragma unroll
  for (int m=0;m<4;++m)
#pragma unroll
    for (int o=0;o<4;++o){ f32x4 z={0.f,0.f,0.f,0.f}; acc[m][o]=z; }

  auto issueW = [&](int t){
    char* buf = smem + (t & 3)*16384 + wv*4096;
    const u16* wb; int k32 = 0; bool x0 = false;
    if (L==0){ if (t==0){ wb=Wi; x0=true; } else { wb=Wh; k32=t-1; } }
    else { if (t<NI){ wb=Wi; k32=t; } else { wb=Wh; k32=t-NI; } }
    int jg = jt*4 + wv;
#pragma unroll
    for (int plane=0; plane<4; ++plane){
      size_t off = x0 ? ((size_t)(jg*4 + plane))*512
                      : ((size_t)((jg*16 + k32)*4 + plane))*512;
      gload16(wb + off + (size_t)lane*8, buf + plane*1024);
    }
  };

  auto issueA = [&](int t){
    char* buf = smem + AOFF + (t & 3)*8192;
    const u16 *phi, *plo; int k32;
    if (L==0){ phi = AhiH; plo = AloH; k32 = (t==0) ? 0 : (t-1); }  // t=0 dummy (x path)
    else if (t < NI){ phi = AhiI; plo = AloI; k32 = t; }
    else { phi = AhiH; plo = AloH; k32 = t - NI; }
    size_t off = ((size_t)((mt*4 + wv)*16 + k32))*512 + (size_t)lane*8;
    gload16(phi + off, buf + (wv*2+0)*1024);
    gload16(plo + off, buf + (wv*2+1)*1024);
  };

  auto compute = [&](int t){
    const char* wbuf = smem + (t & 3)*16384 + wv*4096;
    bf16x8 wf[4];
#pragma unroll
    for (int pl=0; pl<4; ++pl)
      wf[pl] = *(const bf16x8*)(wbuf + pl*1024 + (size_t)lane*16);
    if (L==0 && t==0){
#pragma unroll
      for (int m=0;m<4;++m){
        bf16x8 ax = *(const bf16x8*)(smem + XOFF + m*1024 + (size_t)lane*16);
        acc[m][0] = MFMA(ax, wf[0], acc[m][0]);
        acc[m][1] = MFMA(ax, wf[1], acc[m][1]);
        acc[m][2] = MFMA(ax, wf[2], acc[m][2]);
        acc[m][2] = MFMA(ax, wf[3], acc[m][2]);
      }
    } else {
      const char* abuf = smem + AOFF + (t & 3)*8192;
      int gn = (t < NI) ? 2 : 3;
#pragma unroll
      for (int m=0;m<4;++m){
        bf16x8 ah = *(const bf16x8*)(abuf + (m*2+0)*1024 + (size_t)lane*16);
        bf16x8 al = *(const bf16x8*)(abuf + (m*2+1)*1024 + (size_t)lane*16);
        acc[m][0]  = MFMA(ah, wf[0], acc[m][0]);
        acc[m][0]  = MFMA(al, wf[0], acc[m][0]);
        acc[m][1]  = MFMA(ah, wf[1], acc[m][1]);
        acc[m][1]  = MFMA(al, wf[1], acc[m][1]);
        acc[m][gn] = MFMA(ah, wf[2], acc[m][gn]);
        acc[m][gn] = MFMA(ah, wf[3], acc[m][gn]);
        acc[m][gn] = MFMA(al, wf[2], acc[m][gn]);
      }
    }
  };

  // ---- L0: stage x tile (64 rows) as [x_hi k0-15 | x_lo k16-31] frag-linear
  if (L==0 && tid < 128){
    int row = tid >> 1, half = tid & 1;
    const float* xr = a.x + (size_t)s*Bn*16 + (size_t)(mt*64 + row)*16 + half*8;
    U16x8 H, Lo;
#pragma unroll
    for (int i=0;i<8;++i){ float f = xr[i]; u16 h = f2bf(f); H.u[i]=h; Lo.u[i]=f2bf(f - bf2f(h)); }
    char* b0 = smem + XOFF + (row>>4)*1024;
    *(uint4*)(b0 + (size_t)((row&15) + half*16)*16)     = H.v;
    *(uint4*)(b0 + (size_t)((row&15) + (2+half)*16)*16) = Lo.v;
  }

  // ---- prologue: W prefetch (static data, hides under spin) -> spin ->
  //      acquire fence (wave0) -> barrier -> A prefetch
  issueW(0); issueW(1); issueW(2);
  if (wv == 0){
    if (lane == 0){
      if (sp1) spinw(sp1, 8u);
      if (sp2) spinw(sp2, 8u);
    }
    __builtin_amdgcn_fence(__ATOMIC_ACQUIRE, "agent");
  }
  lgkm0();
  SBAR();
  issueA(0); issueA(1); issueA(2);

  // ---- main loop: wait(counted) -> barrier -> MFMA(t) -> issue(t+3)
#pragma unroll
  for (int t=0; t<NT; ++t){
    int lvl = (t==0) ? 4 : (t==1) ? 8 : (t==NT-1) ? 0 : (t==NT-2) ? 6 : 12;
    vwn(lvl);
    SBAR();
    compute(t);
    if (t+3 < NT){ issueW(t+3); issueA(t+3); }
  }

  // ---- epilogue: gates -> LDS transpose (reuse W slot 0) -> coalesced
  //      plain stores -> release publish
  SBAR();                                    // protect W slot0 readers (NT=17)
  const int col = lane & 15, rg = lane >> 4;
  const int half = wv >> 1;
#pragma unroll
  for (int m=0;m<4;++m){
#pragma unroll
    for (int r=0;r<4;++r){
      float pr  = acc[m][0][r] + SR;
      float pz  = acc[m][1][r] + SZ;
      float pin = acc[m][2][r] + BIN;
      float phn = acc[m][3][r] + BHN;
      float rgt = 1.f/(1.f + __expf(-pr));
      float zgt = 1.f/(1.f + __expf(-pz));
      float e2  = __expf(2.f*(pin + rgt*phn));
      float nn  = 1.f - 2.f/(e2 + 1.f);      // tanh, overflow-safe
      float hv  = hp[m][r];
      float hnv = (1.f - zgt)*nn + zgt*hv;
      hp[m][r] = hnv;
      u16 hi = f2bf(hnv), lo = f2bf(hnv - bf2f(hi));
      int q = (wv*2 + (col>>3)) & 3;
      int inoff = q*128 + (rg*4 + r)*8 + (col & 7);   // u16 units, [0,512)
      int ci = m*2 + half;
      *(u16*)(smem + ci*1024 + inoff*2)        = hi;
      *(u16*)(smem + 8192 + ci*1024 + inoff*2) = lo;
    }
  }
  lgkm0();
  SBAR();
  {
    int ci = tid >> 5, m = ci >> 1, hf = ci & 1;
    const char* sh = smem + ci*1024 + (size_t)(tid & 31)*32;
    const char* sl = sh + 8192;
    u16* dh = OHI + (size_t)(mt*4 + m)*8192 + (size_t)(jt*2 + hf)*512 + (size_t)(tid & 31)*16;
    u16* dl = OLO + (size_t)(mt*4 + m)*8192 + (size_t)(jt*2 + hf)*512 + (size_t)(tid & 31)*16;
    *(uint4*)dh       = *(const uint4*)sh;
    *(uint4*)(dh + 8) = *(const uint4*)(sh + 16);
    *(uint4*)dl       = *(const uint4*)sl;
    *(uint4*)(dl + 8) = *(const uint4*)(sl + 16);
  }
  vw<0>();
  SBAR();
  if (tid == 0){
    __builtin_amdgcn_fence(__ATOMIC_RELEASE, "agent");
    __hip_atomic_fetch_add(pub, 1u, __ATOMIC_RELAXED, __HIP_MEMORY_SCOPE_AGENT);
  }
}

// =====================================================================
// Persistent kernel: 256 blocks (1/CU via 100KB LDS), 512 steps x 2 layers.
// Decode: mt = (bid&7)*4 + ((bid>>3)&3)  (8-jt peer groups share bid%8 ->
// same XCD under round-robin => A-traffic XCD-local), jt = bid>>5.
// =====================================================================
__global__ __launch_bounds__(256, 1) void gru_persist(PA a){
  __shared__ __align__(16) char smem[102400];
  const int tid = threadIdx.x, lane = tid & 63, wv = tid >> 6;
  const int bid = blockIdx.x;
  const int mt = (bid & 7)*4 + ((bid >> 3) & 3);
  const int jt = bid >> 5;

  const int j = jt*64 + wv*16 + (lane & 15);
  const float SR0 = a.bi0[j] + a.bh0[j];
  const float SZ0 = a.bi0[Hn+j] + a.bh0[Hn+j];
  const float BIN0 = a.bi0[2*Hn+j], BHN0 = a.bh0[2*Hn+j];
  const float SR1 = a.bi1[j] + a.bh1[j];
  const float SZ1 = a.bi1[Hn+j] + a.bh1[Hn+j];
  const float BIN1 = a.bi1[2*Hn+j], BHN1 = a.bh1[2*Hn+j];

  f32x4 hp0[4], hp1[4];
#pragma unroll
  for (int m=0;m<4;++m){ f32x4 z={0.f,0.f,0.f,0.f}; hp0[m]=z; hp1[m]=z; }

  u32* f0 = a.flags;
  u32* f1 = a.flags + 16384;

#pragma unroll 1
  for (int s=0; s<Tn; ++s){
    const size_t P0 = (size_t)(s&1)*PLANE, P1 = (size_t)((s&1)^1)*PLANE;
    layer_run<0>(a, s, smem, tid, lane, wv, mt, jt,
                 nullptr, nullptr,
                 a.H0HI + P1, a.H0LO + P1,
                 a.H0HI + P0, a.H0LO + P0,
                 SR0, SZ0, BIN0, BHN0, hp0,
                 (s>0) ? &f0[(size_t)(s-1)*32 + mt] : nullptr, nullptr,
                 &f0[(size_t)s*32 + mt]);
    layer_run<1>(a, s, smem, tid, lane, wv, mt, jt,
                 a.H0HI + P0, a.H0LO + P0,
                 a.H1HI + P1, a.H1LO + P1,
                 a.H1HI + P0, a.H1LO + P0,
                 SR1, SZ1, BIN1, BHN1, hp1,
                 &f0[(size_t)s*32 + mt],
                 (s>0) ? &f1[(size_t)(s-1)*32 + mt] : nullptr,
                 &f1[(size_t)s*32 + mt]);
  }
}

// final projection: out[b][o] = h1[b,:] . Wout[o,:] + bout[o]
__global__ __launch_bounds__(64) void outproj(const u16* __restrict__ h1hi,
                                              const u16* __restrict__ h1lo,
                                              const float* __restrict__ Wout,
                                              const float* __restrict__ bout,
                                              float* __restrict__ out){
  int b = blockIdx.x, l = threadIdx.x;
  float acc[8] = {0.f,0.f,0.f,0.f,0.f,0.f,0.f,0.f};
  for (int jj = l; jj < Hn; jj += 64){
    size_t fo = ((size_t)(b>>4)*16 + (jj>>5))*512 + (size_t)((b&15) + ((jj>>3)&3)*16)*8 + (jj&7);
    float hv = bf2f(h1hi[fo]) + bf2f(h1lo[fo]);
#pragma unroll
    for (int o=0;o<8;++o) acc[o] += hv * Wout[o*Hn + jj];
  }
#pragma unroll
  for (int o=0;o<8;++o){
#pragma unroll
    for (int off=32; off; off>>=1) acc[o] += __shfl_xor(acc[o], off);
  }
  if (l == 0){
#pragma unroll
    for (int o=0;o<8;++o) out[b*8+o] = acc[o] + bout[o];
  }
}

extern "C" void kernel_launch(void* const* d_in, const int* in_sizes, int n_in,
                              void* d_out, int out_size, void* d_ws, size_t ws_size,
                              hipStream_t stream){
  (void)in_sizes; (void)n_in; (void)out_size; (void)ws_size;
  const float* x    = (const float*)d_in[0];
  const float* Wih0 = (const float*)d_in[1];
  const float* Whh0 = (const float*)d_in[2];
  const float* bih0 = (const float*)d_in[3];
  const float* bhh0 = (const float*)d_in[4];
  const float* Wih1 = (const float*)d_in[5];
  const float* Whh1 = (const float*)d_in[6];
  const float* bih1 = (const float*)d_in[7];
  const float* bhh1 = (const float*)d_in[8];
  const float* Wout = (const float*)d_in[9];
  const float* bout = (const float*)d_in[10];
  char* ws = (char*)d_ws;

  prep_w  <<<1536, 256, 0, stream>>>(Whh0, Wih1, Whh1, (u16*)(ws + OFF_WH0));
  prep_wi0<<<  32, 256, 0, stream>>>(Wih0, (u16*)(ws + OFF_WI0));
  zero_ws <<<2080, 256, 0, stream>>>(ws);

  PA pa;
  pa.WI0 = (const u16*)(ws + OFF_WI0);
  pa.WH0 = (const u16*)(ws + OFF_WH0);
  pa.WI1 = (const u16*)(ws + OFF_WI1);
  pa.WH1 = (const u16*)(ws + OFF_WH1);
  pa.x = x;
  pa.H0HI = (u16*)(ws + OFF_H0HI); pa.H0LO = (u16*)(ws + OFF_H0LO);
  pa.H1HI = (u16*)(ws + OFF_H1HI); pa.H1LO = (u16*)(ws + OFF_H1LO);
  pa.flags = (u32*)(ws + OFF_FLAGS);
  pa.bi0 = bih0; pa.bh0 = bhh0; pa.bi1 = bih1; pa.bh1 = bhh1;

  gru_persist<<<256, 256, 0, stream>>>(pa);

  outproj<<<2048, 64, 0, stream>>>(
      (const u16*)(ws + OFF_H1HI) + PLANE,
      (const u16*)(ws + OFF_H1LO) + PLANE,
      Wout, bout, (float*)d_out);
}